// Round 3
// baseline (1706.117 us; speedup 1.0000x reference)
//
#include <hip/hip_runtime.h>
#include <hip/hip_bf16.h>

typedef __hip_bfloat16 bf16;

// ---------------------------------------------------------------------------
// k_wt: transpose w1 (64,64,3,3) -> w1T[(ic*9+tap)*64 + oc]
// ---------------------------------------------------------------------------
__global__ __launch_bounds__(256) void k_wt(const float* __restrict__ w1,
                                            float* __restrict__ w1T) {
    int i = blockIdx.x * 256 + threadIdx.x;  // i = oc*576 + (ic*9+tap)
    if (i >= 64 * 64 * 9) return;
    int oc = i / 576, rem = i - oc * 576;
    w1T[rem * 64 + oc] = w1[i];
}

// ---------------------------------------------------------------------------
// k_conv1: 3x3 conv (pad1) + bias + BN + ReLU6 + per-pixel channel L2-norm.
// Writes xn (nb,64,256,256) bf16 (internal tensor only).
// ---------------------------------------------------------------------------
__global__ __launch_bounds__(256) void k_conv1(
    const float* __restrict__ feat_c, const float* __restrict__ w1T,
    const float* __restrict__ b1, const float* __restrict__ gamma,
    const float* __restrict__ beta, const float* __restrict__ rmean,
    const float* __restrict__ rvar, bf16* __restrict__ xn) {
    __shared__ __align__(16) float s_in[8][324];   // 8 ch x 18x18
    __shared__ __align__(16) float s_w[72][64];    // (ic_local*9+tap) x oc
    __shared__ float2 s_bn[64];

    const int b = blockIdx.z;        // local image in chunk
    const int x0 = blockIdx.x * 16, y0 = blockIdx.y * 16;
    const int tid = threadIdx.x;
    const int tx = tid & 15, ty = tid >> 4;

    if (tid < 64) {
        float inv = 1.0f / sqrtf(rvar[tid] + 1e-5f);
        float sA = inv * gamma[tid];
        float sB = (b1[tid] - rmean[tid]) * sA + beta[tid];
        s_bn[tid] = make_float2(sA, sB);
    }

    float acc[64];
#pragma unroll
    for (int o = 0; o < 64; o++) acc[o] = 0.f;

    const float* featb = feat_c + (size_t)b * 64 * 65536;

    for (int c0 = 0; c0 < 64; c0 += 8) {
        __syncthreads();
        {   // weights: rows c0*9 .. c0*9+71 of w1T (contiguous 4608 floats)
            const float4* wsrc = (const float4*)(w1T + c0 * 576);
            float4* wdst = (float4*)&s_w[0][0];
            for (int i = tid; i < 1152; i += 256) wdst[i] = wsrc[i];
        }
        for (int i = tid; i < 2592; i += 256) {  // 8 ch x 18x18 input tile
            int ic = i / 324, r = i - ic * 324;
            int ry = r / 18, rx = r - ry * 18;
            int yy = y0 - 1 + ry, xx = x0 - 1 + rx;
            float v = 0.f;
            if ((unsigned)yy < 256u && (unsigned)xx < 256u)
                v = featb[(size_t)(c0 + ic) * 65536 + yy * 256 + xx];
            s_in[ic][r] = v;
        }
        __syncthreads();
        for (int ic = 0; ic < 8; ++ic) {
            const float* srow = &s_in[ic][ty * 18 + tx];
#pragma unroll
            for (int t = 0; t < 9; t++) {
                float v = srow[(t / 3) * 18 + (t % 3)];
                const float4* wp4 = (const float4*)&s_w[ic * 9 + t][0];
#pragma unroll
                for (int o4 = 0; o4 < 16; o4++) {
                    float4 wv = wp4[o4];
                    acc[o4 * 4 + 0] = fmaf(wv.x, v, acc[o4 * 4 + 0]);
                    acc[o4 * 4 + 1] = fmaf(wv.y, v, acc[o4 * 4 + 1]);
                    acc[o4 * 4 + 2] = fmaf(wv.z, v, acc[o4 * 4 + 2]);
                    acc[o4 * 4 + 3] = fmaf(wv.w, v, acc[o4 * 4 + 3]);
                }
            }
        }
    }

    float ssum = 0.f;
#pragma unroll
    for (int o = 0; o < 64; o++) {
        float2 bn = s_bn[o];
        float v = fmaf(acc[o], bn.x, bn.y);
        v = fminf(fmaxf(v, 0.f), 6.f);
        acc[o] = v;
        ssum = fmaf(v, v, ssum);
    }
    float nrm = sqrtf(ssum);
    float sc = (nrm > 0.09f) ? (1.0f / (nrm + 9e-8f)) : 0.f;

    bf16* xb = xn + (size_t)b * 64 * 65536 + (size_t)(y0 + ty) * 256 + (x0 + tx);
#pragma unroll
    for (int o = 0; o < 64; o++)
        xb[(size_t)o * 65536] = __float2bfloat16(acc[o] * sc);
}

// ---------------------------------------------------------------------------
// k_conv2: 5x5 valid conv 64->2 + bias + sigmoid. Output (nb,2,252,252) f32.
// ---------------------------------------------------------------------------
__global__ __launch_bounds__(256) void k_conv2(const bf16* __restrict__ xn,
                                               const float* __restrict__ w2,
                                               const float* __restrict__ b2,
                                               float* __restrict__ dmap_raw) {
    __shared__ float s_in[8][400];   // 8 ch x 20x20
    __shared__ float2 s_w[1600];     // (ic*25+tap) -> (w_oc0, w_oc1)

    const int b = blockIdx.z;
    const int bx = blockIdx.x, by = blockIdx.y;
    const int tid = threadIdx.x;
    const int tx = tid & 15, ty = tid >> 4;
    const int ox = bx * 16 + tx, oy = by * 16 + ty;

    for (int i = tid; i < 1600; i += 256)
        s_w[i] = make_float2(w2[i], w2[1600 + i]);

    float a0 = 0.f, a1 = 0.f;
    const bf16* xb = xn + (size_t)b * 64 * 65536;

    for (int c0 = 0; c0 < 64; c0 += 8) {
        __syncthreads();
        for (int i = tid; i < 3200; i += 256) {
            int ic = i / 400, r = i - ic * 400;
            int yy = by * 16 + r / 20, xx = bx * 16 + r % 20;
            float v = 0.f;
            if (yy < 256 && xx < 256)
                v = __bfloat162float(xb[(size_t)(c0 + ic) * 65536 + yy * 256 + xx]);
            s_in[ic][r] = v;
        }
        __syncthreads();
        for (int ic = 0; ic < 8; ic++) {
            const float* base = &s_in[ic][ty * 20 + tx];
            const float2* wp = &s_w[(c0 + ic) * 25];
#pragma unroll
            for (int t = 0; t < 25; t++) {
                float v = base[(t / 5) * 20 + (t % 5)];
                float2 wv = wp[t];
                a0 = fmaf(wv.x, v, a0);
                a1 = fmaf(wv.y, v, a1);
            }
        }
    }

    if (ox < 252 && oy < 252) {
        size_t o = (size_t)(b * 2) * 63504 + (size_t)oy * 252 + ox;
        float v0 = a0 + b2[0], v1 = a1 + b2[1];
        dmap_raw[o] = 1.f / (1.f + expf(-v0));
        dmap_raw[o + 63504] = 1.f / (1.f + expf(-v1));
    }
}

// ---------------------------------------------------------------------------
// k_nearest: 252x252 -> 130x130 nearest + 0.0009 + HARDNESS*interior_mask.
// ---------------------------------------------------------------------------
__global__ __launch_bounds__(256) void k_nearest(const float* __restrict__ dmap_raw,
                                                 float* __restrict__ dmapA,
                                                 int total) {
    int i = blockIdx.x * 256 + threadIdx.x;
    if (i >= total) return;
    int ox = i % 130;
    int t = i / 130;
    int oy = t % 130;
    int bc = t / 130;
    const float SC = (float)(252.0 / 130.0);
    int sy = (int)floorf((float)oy * SC);
    int sx = (int)floorf((float)ox * SC);
    float v = dmap_raw[(size_t)bc * 63504 + sy * 252 + sx];
    float m = (oy >= 1 && oy <= 128 && ox >= 1 && ox <= 128) ? 2.0f : 0.0f;
    dmapA[i] = v + 0.0009f + m;
}

// ---------------------------------------------------------------------------
// k_bilinear: jax.image.resize(linear, antialias=False) equivalent (clamped
// bilerp; edge renormalization == clamping for the linear kernel here).
// ---------------------------------------------------------------------------
__global__ __launch_bounds__(256) void k_bilinear(const float* __restrict__ in,
                                                  float* __restrict__ out,
                                                  int IH, int IW, int OH, int OW,
                                                  float sch, float scw, int total) {
    int i = blockIdx.x * 256 + threadIdx.x;
    if (i >= total) return;
    int ox = i % OW;
    int t = i / OW;
    int oy = t % OH;
    int bc = t / OH;
    float sy = ((float)oy + 0.5f) * sch - 0.5f;
    float sx = ((float)ox + 0.5f) * scw - 0.5f;
    float y0f = floorf(sy), x0f = floorf(sx);
    float wy = sy - y0f, wx = sx - x0f;
    int y0 = (int)y0f, x0 = (int)x0f;
    int y1 = y0 + 1, x1 = x0 + 1;
    y0 = max(min(y0, IH - 1), 0);
    y1 = max(min(y1, IH - 1), 0);
    x0 = max(min(x0, IW - 1), 0);
    x1 = max(min(x1, IW - 1), 0);
    const float* p = in + (size_t)bc * IH * IW;
    float top = p[y0 * IW + x0] * (1.f - wx) + p[y0 * IW + x1] * wx;
    float bot = p[y1 * IW + x0] * (1.f - wx) + p[y1 * IW + x1] * wx;
    out[i] = top * (1.f - wy) + bot * wy;
}

// ---------------------------------------------------------------------------
// k_grid: per image, normalize + cumsum -> grid (nb,128,128,2), ch0=wc, ch1=hc.
// Reads the 130x130 dmap (f32) straight from the output buffer region.
// ---------------------------------------------------------------------------
__global__ __launch_bounds__(256) void k_grid(const float* __restrict__ dmap130,
                                              float* __restrict__ grid) {
    int b = blockIdx.x;
    int t = threadIdx.x;
    if (t >= 130) return;
    const float* h = dmap130 + (size_t)(b * 2 + 0) * 16900;
    const float* w = dmap130 + (size_t)(b * 2 + 1) * 16900;
    float* g = grid + (size_t)b * 128 * 128 * 2;

    {   // h: column t, normalize by column sum (axis 2), cumsum down rows
        float s = 0.f;
        for (int r = 0; r < 130; r++) s += h[r * 130 + t];
        float inv = 1.f / s;
        float c = 0.f;
        for (int r = 0; r < 130; r++) {
            c += h[r * 130 + t] * inv;
            if (r >= 1 && r <= 128 && t >= 1 && t <= 128)
                g[((r - 1) * 128 + (t - 1)) * 2 + 1] = c * 2.f - 1.f;
        }
    }
    {   // w: row t, normalize by row sum (axis 3), cumsum across cols
        const float* wrow = w + t * 130;
        float s = 0.f;
        for (int x = 0; x < 130; x++) s += wrow[x];
        float inv = 1.f / s;
        float c = 0.f;
        for (int x = 0; x < 130; x++) {
            c += wrow[x] * inv;
            if (x >= 1 && x <= 128 && t >= 1 && t <= 128)
                g[((t - 1) * 128 + (x - 1)) * 2 + 0] = c * 2.f - 1.f;
        }
    }
}

// ---------------------------------------------------------------------------
// k_sample: grid_sample_bilinear(feat, grid) -> dst (nb,64,128,128) f32.
// ---------------------------------------------------------------------------
__global__ __launch_bounds__(256) void k_sample(const float* __restrict__ feat_c,
                                                const float* __restrict__ grid,
                                                float* __restrict__ dst_c) {
    const int b = blockIdx.z;
    const int x = blockIdx.x * 16 + (threadIdx.x & 15);
    const int y = blockIdx.y * 16 + (threadIdx.x >> 4);

    const float* g = grid + (((size_t)b * 128 + y) * 128 + x) * 2;
    float gx = g[0], gy = g[1];
    float ix = (gx + 1.f) * 128.f - 0.5f;  // W*0.5 = 128
    float iy = (gy + 1.f) * 128.f - 0.5f;
    float x0f = floorf(ix), y0f = floorf(iy);
    float wx = ix - x0f, wy = iy - y0f;
    int ix0 = (int)x0f, iy0 = (int)y0f;
    int ix1 = ix0 + 1, iy1 = iy0 + 1;
    float vx0 = ((unsigned)ix0 < 256u) ? 1.f : 0.f;
    float vx1 = ((unsigned)ix1 < 256u) ? 1.f : 0.f;
    float vy0 = ((unsigned)iy0 < 256u) ? 1.f : 0.f;
    float vy1 = ((unsigned)iy1 < 256u) ? 1.f : 0.f;
    int cx0 = max(min(ix0, 255), 0), cx1 = max(min(ix1, 255), 0);
    int cy0 = max(min(iy0, 255), 0), cy1 = max(min(iy1, 255), 0);
    float w00 = (1.f - wx) * (1.f - wy) * vx0 * vy0;
    float w01 = wx * (1.f - wy) * vx1 * vy0;
    float w10 = (1.f - wx) * wy * vx0 * vy1;
    float w11 = wx * wy * vx1 * vy1;

    const float* fb = feat_c + (size_t)b * 64 * 65536;
    int o00 = cy0 * 256 + cx0, o01 = cy0 * 256 + cx1;
    int o10 = cy1 * 256 + cx0, o11 = cy1 * 256 + cx1;
    float* d = dst_c + (size_t)b * 64 * 16384 + (size_t)y * 128 + x;
#pragma unroll 4
    for (int c = 0; c < 64; c++) {
        const float* fc = fb + (size_t)c * 65536;
        d[(size_t)c * 16384] = fc[o00] * w00 + fc[o01] * w01 +
                               fc[o10] * w10 + fc[o11] * w11;
    }
}

// ---------------------------------------------------------------------------
static inline size_t align256(size_t x) { return (x + 255) & ~(size_t)255; }

extern "C" void kernel_launch(void* const* d_in, const int* in_sizes, int n_in,
                              void* d_out, int out_size, void* d_ws, size_t ws_size,
                              hipStream_t stream) {
    const float* feat  = (const float*)d_in[0];
    const float* w1    = (const float*)d_in[1];
    const float* b1    = (const float*)d_in[2];
    const float* gamma = (const float*)d_in[3];
    const float* beta  = (const float*)d_in[4];
    const float* rmean = (const float*)d_in[5];
    const float* rvar  = (const float*)d_in[6];
    const float* w2    = (const float*)d_in[7];
    const float* b2    = (const float*)d_in[8];

    float* out = (float*)d_out;                 // reference outputs are f32
    float* out_dst  = out;                      // (16,64,128,128)
    float* out_dmap = out + 16777216;           // (16,2,130,130)

    // pick images-per-chunk nb adaptively from ws_size (deterministic)
    int nb = 1;
    const int cands[5] = {16, 8, 4, 2, 1};
    for (int k = 0; k < 5; ++k) {
        int n = cands[k];
        size_t need = align256((size_t)n * 16777216)      // xn  bf16
                    + align256(147456ull * 4 / 4)         // w1T (147,456 B)
                    + align256((size_t)n * 2 * 63504 * 4) // dmap_raw
                    + align256((size_t)n * 2 * 16900 * 4) // dmapA
                    + align256((size_t)n * 2 * 16384 * 4) // dsm
                    + align256((size_t)n * 128 * 128 * 2 * 4); // grid
        if (need <= ws_size) { nb = n; break; }
    }

    char* p = (char*)d_ws;
    bf16*  xn       = (bf16*)p;  p += align256((size_t)nb * 16777216);
    float* w1T      = (float*)p; p += align256(147456);
    float* dmap_raw = (float*)p; p += align256((size_t)nb * 2 * 63504 * 4);
    float* dmapA    = (float*)p; p += align256((size_t)nb * 2 * 16900 * 4);
    float* dsm      = (float*)p; p += align256((size_t)nb * 2 * 16384 * 4);
    float* grid     = (float*)p;

    k_wt<<<(36864 + 255) / 256, 256, 0, stream>>>(w1, w1T);

    const int nchunks = 16 / nb;
    for (int c = 0; c < nchunks; ++c) {
        const float* feat_c = feat + (size_t)c * nb * 64 * 65536;
        float* dst_c  = out_dst  + (size_t)c * nb * 64 * 16384;
        float* dmap_c = out_dmap + (size_t)c * nb * 2 * 16900;

        k_conv1<<<dim3(16, 16, nb), 256, 0, stream>>>(feat_c, w1T, b1, gamma,
                                                      beta, rmean, rvar, xn);
        k_conv2<<<dim3(16, 16, nb), 256, 0, stream>>>(xn, w2, b2, dmap_raw);
        k_nearest<<<(nb * 2 * 16900 + 255) / 256, 256, 0, stream>>>(
            dmap_raw, dmapA, nb * 2 * 16900);
        k_bilinear<<<(nb * 2 * 16384 + 255) / 256, 256, 0, stream>>>(
            dmapA, dsm, 130, 130, 128, 128,
            (float)(130.0 / 128.0), (float)(130.0 / 128.0), nb * 2 * 16384);
        k_bilinear<<<(nb * 2 * 16900 + 255) / 256, 256, 0, stream>>>(
            dsm, dmap_c, 128, 128, 130, 130,
            (float)(128.0 / 130.0), (float)(128.0 / 130.0), nb * 2 * 16900);
        k_grid<<<nb, 256, 0, stream>>>(dmap_c, grid);
        k_sample<<<dim3(8, 8, nb), 256, 0, stream>>>(feat_c, grid, dst_c);
    }
}

// Round 4
// 824.255 us; speedup vs baseline: 2.0699x; 2.0699x over previous
//
#include <hip/hip_runtime.h>
#include <hip/hip_bf16.h>

typedef __hip_bfloat16 bf16;
typedef __attribute__((ext_vector_type(8))) short bf16x8;
typedef __attribute__((ext_vector_type(4))) float f32x4;

static __device__ __forceinline__ ushort f2bf(float f) {
    uint u = __float_as_uint(f);
    u += 0x7fff + ((u >> 16) & 1);   // RNE
    return (ushort)(u >> 16);
}

// ---------------------------------------------------------------------------
// k_wt: w1 (oc,ic,3,3) f32 -> w_bf[tap][oc][ic ^ ((oc&7)<<3)] bf16
// (pre-swizzled so conv1's LDS weight staging is a linear copy)
// ---------------------------------------------------------------------------
__global__ __launch_bounds__(256) void k_wt(const float* __restrict__ w1,
                                            ushort* __restrict__ w_bf) {
    int i = blockIdx.x * 256 + threadIdx.x;   // i = ((oc*64+ic)*3+dy)*3+dx
    if (i >= 36864) return;
    int oc = i / 576, rem = i - oc * 576;
    int ic = rem / 9, tap = rem - ic * 9;
    w_bf[tap * 4096 + oc * 64 + (ic ^ ((oc & 7) << 3))] = f2bf(w1[i]);
}

// ---------------------------------------------------------------------------
// k_conv1 (MFMA): 3x3 conv (pad1) + bias + BN + ReLU6 + channel L2-norm.
// Block: 256 thr = 4 waves; tile = 4 rows x 64 cols x 64 oc. Wave w owns row
// y0+w. GEMM: M=pixels, N=oc, K=(tap,ic). 16x16x32 bf16 MFMA, 4x4 frags.
// ---------------------------------------------------------------------------
__global__ __launch_bounds__(256, 2) void k_conv1(
    const float* __restrict__ feat_c, const ushort* __restrict__ w_bf,
    const float* __restrict__ b1, const float* __restrict__ gamma,
    const float* __restrict__ beta, const float* __restrict__ rmean,
    const float* __restrict__ rvar, ushort* __restrict__ xn) {
    __shared__ uint s_in2[6 * 66 * 32];   // rows y0-1..y0+4, cols x0-1..x0+64, 64 ic bf16 (swizzled)
    __shared__ uint s_w2[3 * 64 * 32];    // [dx][oc][ic] bf16, pre-swizzled
    __shared__ float2 s_bn[64];

    const int b   = blockIdx.z;
    const int x0  = blockIdx.x * 64;
    const int y0  = blockIdx.y * 4;
    const int tid = threadIdx.x;
    const int lane = tid & 63;
    const int w    = tid >> 6;
    const int l15  = lane & 15;
    const int l4   = lane >> 4;

    if (tid < 64) {
        float inv = 1.0f / sqrtf(rvar[tid] + 1e-5f);
        float sA = inv * gamma[tid];
        float sB = (b1[tid] - rmean[tid]) * sA + beta[tid];
        s_bn[tid] = make_float2(sA, sB);
    }

    const float* featb = feat_c + (size_t)b * 64 * 65536;

    // stage input tile (f32 -> bf16 pairs, ic-transposed, XOR-swizzled)
    for (int i = tid; i < 12672; i += 256) {
        int c = i % 66;
        int rest = i / 66;
        int r = rest % 6;
        int icp = rest / 6;                 // ic pair: ic = 2*icp, 2*icp+1
        int y = y0 - 1 + r, x = x0 - 1 + c;
        float v0 = 0.f, v1 = 0.f;
        if ((unsigned)y < 256u && (unsigned)x < 256u) {
            const float* p = featb + (size_t)icp * 131072 + y * 256 + x;
            v0 = p[0];
            v1 = p[65536];
        }
        s_in2[(r * 66 + c) * 32 + (icp ^ ((c & 7) << 2))] =
            (uint)f2bf(v0) | ((uint)f2bf(v1) << 16);
    }

    f32x4 acc[4][4];
#pragma unroll
    for (int m = 0; m < 4; m++)
#pragma unroll
        for (int n = 0; n < 4; n++) acc[m][n] = (f32x4){0.f, 0.f, 0.f, 0.f};

    for (int dy = 0; dy < 3; dy++) {
        __syncthreads();   // prev chunk's reads done (and s_in ready on iter 0)
        {   // weights chunk dy: linear 24576 B copy (pre-swizzled in global)
            const uint4* src = (const uint4*)(w_bf + dy * 12288);
            uint4* dst = (uint4*)s_w2;
            for (int i = tid; i < 1536; i += 256) dst[i] = src[i];
        }
        __syncthreads();
#pragma unroll
        for (int dx = 0; dx < 3; dx++) {
#pragma unroll
            for (int ks = 0; ks < 2; ks++) {   // two K=32 steps over 64 ic
                bf16x8 a[4], bb[4];
#pragma unroll
                for (int m = 0; m < 4; m++) {
                    int c = m * 16 + l15 + dx;
                    int idx = ((w + dy) * 66 + c) * 32 +
                              ((ks * 16 + l4 * 4) ^ ((c & 7) << 2));
                    a[m] = *(const bf16x8*)&s_in2[idx];
                }
#pragma unroll
                for (int n = 0; n < 4; n++) {
                    int oc = n * 16 + l15;
                    int idx = (dx * 64 + oc) * 32 +
                              ((ks * 16 + l4 * 4) ^ ((oc & 7) << 2));
                    bb[n] = *(const bf16x8*)&s_w2[idx];
                }
#pragma unroll
                for (int m = 0; m < 4; m++)
#pragma unroll
                    for (int n = 0; n < 4; n++)
                        acc[m][n] = __builtin_amdgcn_mfma_f32_16x16x32_bf16(
                            a[m], bb[n], acc[m][n], 0, 0, 0);
            }
        }
    }

    // epilogue: BN + ReLU6 + L2-norm (16-lane oc-group reduce) + bf16 store
    float sA[4], sB[4];
#pragma unroll
    for (int n = 0; n < 4; n++) {
        float2 t = s_bn[n * 16 + l15];
        sA[n] = t.x; sB[n] = t.y;
    }
    const int y = y0 + w;
    ushort* xb = xn + (size_t)b * 64 * 65536;

#pragma unroll
    for (int m = 0; m < 4; m++) {
        float vv[4][4];   // [j][n]
        float scj[4];
#pragma unroll
        for (int j = 0; j < 4; j++) {
            float ss = 0.f;
#pragma unroll
            for (int n = 0; n < 4; n++) {
                float v = fmaf(acc[m][n][j], sA[n], sB[n]);
                v = fminf(fmaxf(v, 0.f), 6.f);
                vv[j][n] = v;
                ss = fmaf(v, v, ss);
            }
            ss += __shfl_xor(ss, 1);
            ss += __shfl_xor(ss, 2);
            ss += __shfl_xor(ss, 4);
            ss += __shfl_xor(ss, 8);
            float nrm = sqrtf(ss);
            scj[j] = (nrm > 0.09f) ? (1.0f / (nrm + 9e-8f)) : 0.f;
        }
        int xbase = x0 + m * 16 + l4 * 4;   // j=0..3 are consecutive x
#pragma unroll
        for (int n = 0; n < 4; n++) {
            uint2 pk;
            pk.x = (uint)f2bf(vv[0][n] * scj[0]) | ((uint)f2bf(vv[1][n] * scj[1]) << 16);
            pk.y = (uint)f2bf(vv[2][n] * scj[2]) | ((uint)f2bf(vv[3][n] * scj[3]) << 16);
            *(uint2*)(xb + (size_t)(n * 16 + l15) * 65536 + y * 256 + xbase) = pk;
        }
    }
}

// ---------------------------------------------------------------------------
// k_conv2: 5x5 valid conv 64->2 + bias + sigmoid. Output (nb,2,252,252) f32.
// ---------------------------------------------------------------------------
__global__ __launch_bounds__(256) void k_conv2(const bf16* __restrict__ xn,
                                               const float* __restrict__ w2,
                                               const float* __restrict__ b2,
                                               float* __restrict__ dmap_raw) {
    __shared__ float s_in[8][400];   // 8 ch x 20x20
    __shared__ float2 s_w[1600];     // (ic*25+tap) -> (w_oc0, w_oc1)

    const int b = blockIdx.z;
    const int bx = blockIdx.x, by = blockIdx.y;
    const int tid = threadIdx.x;
    const int tx = tid & 15, ty = tid >> 4;
    const int ox = bx * 16 + tx, oy = by * 16 + ty;

    for (int i = tid; i < 1600; i += 256)
        s_w[i] = make_float2(w2[i], w2[1600 + i]);

    float a0 = 0.f, a1 = 0.f;
    const bf16* xb = xn + (size_t)b * 64 * 65536;

    for (int c0 = 0; c0 < 64; c0 += 8) {
        __syncthreads();
        for (int i = tid; i < 3200; i += 256) {
            int ic = i / 400, r = i - ic * 400;
            int yy = by * 16 + r / 20, xx = bx * 16 + r % 20;
            float v = 0.f;
            if (yy < 256 && xx < 256)
                v = __bfloat162float(xb[(size_t)(c0 + ic) * 65536 + yy * 256 + xx]);
            s_in[ic][r] = v;
        }
        __syncthreads();
        for (int ic = 0; ic < 8; ic++) {
            const float* base = &s_in[ic][ty * 20 + tx];
            const float2* wp = &s_w[(c0 + ic) * 25];
#pragma unroll
            for (int t = 0; t < 25; t++) {
                float v = base[(t / 5) * 20 + (t % 5)];
                float2 wv = wp[t];
                a0 = fmaf(wv.x, v, a0);
                a1 = fmaf(wv.y, v, a1);
            }
        }
    }

    if (ox < 252 && oy < 252) {
        size_t o = (size_t)(b * 2) * 63504 + (size_t)oy * 252 + ox;
        float v0 = a0 + b2[0], v1 = a1 + b2[1];
        dmap_raw[o] = 1.f / (1.f + expf(-v0));
        dmap_raw[o + 63504] = 1.f / (1.f + expf(-v1));
    }
}

// ---------------------------------------------------------------------------
// k_nearest: 252x252 -> 130x130 nearest + 0.0009 + HARDNESS*interior_mask.
// ---------------------------------------------------------------------------
__global__ __launch_bounds__(256) void k_nearest(const float* __restrict__ dmap_raw,
                                                 float* __restrict__ dmapA,
                                                 int total) {
    int i = blockIdx.x * 256 + threadIdx.x;
    if (i >= total) return;
    int ox = i % 130;
    int t = i / 130;
    int oy = t % 130;
    int bc = t / 130;
    const float SC = (float)(252.0 / 130.0);
    int sy = (int)floorf((float)oy * SC);
    int sx = (int)floorf((float)ox * SC);
    float v = dmap_raw[(size_t)bc * 63504 + sy * 252 + sx];
    float m = (oy >= 1 && oy <= 128 && ox >= 1 && ox <= 128) ? 2.0f : 0.0f;
    dmapA[i] = v + 0.0009f + m;
}

// ---------------------------------------------------------------------------
// k_bilinear: jax.image.resize(linear, antialias=False) equivalent.
// ---------------------------------------------------------------------------
__global__ __launch_bounds__(256) void k_bilinear(const float* __restrict__ in,
                                                  float* __restrict__ out,
                                                  int IH, int IW, int OH, int OW,
                                                  float sch, float scw, int total) {
    int i = blockIdx.x * 256 + threadIdx.x;
    if (i >= total) return;
    int ox = i % OW;
    int t = i / OW;
    int oy = t % OH;
    int bc = t / OH;
    float sy = ((float)oy + 0.5f) * sch - 0.5f;
    float sx = ((float)ox + 0.5f) * scw - 0.5f;
    float y0f = floorf(sy), x0f = floorf(sx);
    float wy = sy - y0f, wx = sx - x0f;
    int y0 = (int)y0f, x0 = (int)x0f;
    int y1 = y0 + 1, x1 = x0 + 1;
    y0 = max(min(y0, IH - 1), 0);
    y1 = max(min(y1, IH - 1), 0);
    x0 = max(min(x0, IW - 1), 0);
    x1 = max(min(x1, IW - 1), 0);
    const float* p = in + (size_t)bc * IH * IW;
    float top = p[y0 * IW + x0] * (1.f - wx) + p[y0 * IW + x1] * wx;
    float bot = p[y1 * IW + x0] * (1.f - wx) + p[y1 * IW + x1] * wx;
    out[i] = top * (1.f - wy) + bot * wy;
}

// ---------------------------------------------------------------------------
// k_grid: per image, normalize + cumsum -> grid (nb,128,128,2), ch0=wc, ch1=hc.
// ---------------------------------------------------------------------------
__global__ __launch_bounds__(256) void k_grid(const float* __restrict__ dmap130,
                                              float* __restrict__ grid) {
    int b = blockIdx.x;
    int t = threadIdx.x;
    if (t >= 130) return;
    const float* h = dmap130 + (size_t)(b * 2 + 0) * 16900;
    const float* w = dmap130 + (size_t)(b * 2 + 1) * 16900;
    float* g = grid + (size_t)b * 128 * 128 * 2;

    {   // h: column t, normalize by column sum (axis 2), cumsum down rows
        float s = 0.f;
        for (int r = 0; r < 130; r++) s += h[r * 130 + t];
        float inv = 1.f / s;
        float c = 0.f;
        for (int r = 0; r < 130; r++) {
            c += h[r * 130 + t] * inv;
            if (r >= 1 && r <= 128 && t >= 1 && t <= 128)
                g[((r - 1) * 128 + (t - 1)) * 2 + 1] = c * 2.f - 1.f;
        }
    }
    {   // w: row t, normalize by row sum (axis 3), cumsum across cols
        const float* wrow = w + t * 130;
        float s = 0.f;
        for (int x = 0; x < 130; x++) s += wrow[x];
        float inv = 1.f / s;
        float c = 0.f;
        for (int x = 0; x < 130; x++) {
            c += wrow[x] * inv;
            if (x >= 1 && x <= 128 && t >= 1 && t <= 128)
                g[((t - 1) * 128 + (x - 1)) * 2 + 0] = c * 2.f - 1.f;
        }
    }
}

// ---------------------------------------------------------------------------
// k_sample: grid_sample_bilinear(feat, grid) -> dst (nb,64,128,128) f32.
// ---------------------------------------------------------------------------
__global__ __launch_bounds__(256) void k_sample(const float* __restrict__ feat_c,
                                                const float* __restrict__ grid,
                                                float* __restrict__ dst_c) {
    const int b = blockIdx.z;
    const int x = blockIdx.x * 16 + (threadIdx.x & 15);
    const int y = blockIdx.y * 16 + (threadIdx.x >> 4);

    const float* g = grid + (((size_t)b * 128 + y) * 128 + x) * 2;
    float gx = g[0], gy = g[1];
    float ix = (gx + 1.f) * 128.f - 0.5f;
    float iy = (gy + 1.f) * 128.f - 0.5f;
    float x0f = floorf(ix), y0f = floorf(iy);
    float wx = ix - x0f, wy = iy - y0f;
    int ix0 = (int)x0f, iy0 = (int)y0f;
    int ix1 = ix0 + 1, iy1 = iy0 + 1;
    float vx0 = ((unsigned)ix0 < 256u) ? 1.f : 0.f;
    float vx1 = ((unsigned)ix1 < 256u) ? 1.f : 0.f;
    float vy0 = ((unsigned)iy0 < 256u) ? 1.f : 0.f;
    float vy1 = ((unsigned)iy1 < 256u) ? 1.f : 0.f;
    int cx0 = max(min(ix0, 255), 0), cx1 = max(min(ix1, 255), 0);
    int cy0 = max(min(iy0, 255), 0), cy1 = max(min(iy1, 255), 0);
    float w00 = (1.f - wx) * (1.f - wy) * vx0 * vy0;
    float w01 = wx * (1.f - wy) * vx1 * vy0;
    float w10 = (1.f - wx) * wy * vx0 * vy1;
    float w11 = wx * wy * vx1 * vy1;

    const float* fb = feat_c + (size_t)b * 64 * 65536;
    int o00 = cy0 * 256 + cx0, o01 = cy0 * 256 + cx1;
    int o10 = cy1 * 256 + cx0, o11 = cy1 * 256 + cx1;
    float* d = dst_c + (size_t)b * 64 * 16384 + (size_t)y * 128 + x;
#pragma unroll 4
    for (int c = 0; c < 64; c++) {
        const float* fc = fb + (size_t)c * 65536;
        d[(size_t)c * 16384] = fc[o00] * w00 + fc[o01] * w01 +
                               fc[o10] * w10 + fc[o11] * w11;
    }
}

// ---------------------------------------------------------------------------
static inline size_t align256(size_t x) { return (x + 255) & ~(size_t)255; }

extern "C" void kernel_launch(void* const* d_in, const int* in_sizes, int n_in,
                              void* d_out, int out_size, void* d_ws, size_t ws_size,
                              hipStream_t stream) {
    const float* feat  = (const float*)d_in[0];
    const float* w1    = (const float*)d_in[1];
    const float* b1    = (const float*)d_in[2];
    const float* gamma = (const float*)d_in[3];
    const float* beta  = (const float*)d_in[4];
    const float* rmean = (const float*)d_in[5];
    const float* rvar  = (const float*)d_in[6];
    const float* w2    = (const float*)d_in[7];
    const float* b2    = (const float*)d_in[8];

    float* out = (float*)d_out;                 // reference outputs are f32
    float* out_dst  = out;                      // (16,64,128,128)
    float* out_dmap = out + 16777216;           // (16,2,130,130)

    // pick images-per-chunk nb adaptively from ws_size (deterministic)
    int nb = 1;
    const int cands[5] = {16, 8, 4, 2, 1};
    for (int k = 0; k < 5; ++k) {
        int n = cands[k];
        size_t need = align256((size_t)n * 8388608)        // xn  bf16
                    + align256(73728)                      // w_bf
                    + align256((size_t)n * 2 * 63504 * 4)  // dmap_raw
                    + align256((size_t)n * 2 * 16900 * 4)  // dmapA
                    + align256((size_t)n * 2 * 16384 * 4)  // dsm
                    + align256((size_t)n * 131072);        // grid
        if (need <= ws_size) { nb = n; break; }
    }

    char* p = (char*)d_ws;
    ushort* xn      = (ushort*)p; p += align256((size_t)nb * 8388608);
    ushort* w_bf    = (ushort*)p; p += align256(73728);
    float* dmap_raw = (float*)p;  p += align256((size_t)nb * 2 * 63504 * 4);
    float* dmapA    = (float*)p;  p += align256((size_t)nb * 2 * 16900 * 4);
    float* dsm      = (float*)p;  p += align256((size_t)nb * 2 * 16384 * 4);
    float* grid     = (float*)p;

    k_wt<<<144, 256, 0, stream>>>(w1, w_bf);

    const int nchunks = 16 / nb;
    for (int c = 0; c < nchunks; ++c) {
        const float* feat_c = feat + (size_t)c * nb * 64 * 65536;
        float* dst_c  = out_dst  + (size_t)c * nb * 64 * 16384;
        float* dmap_c = out_dmap + (size_t)c * nb * 2 * 16900;

        k_conv1<<<dim3(4, 64, nb), 256, 0, stream>>>(feat_c, w_bf, b1, gamma,
                                                     beta, rmean, rvar, xn);
        k_conv2<<<dim3(16, 16, nb), 256, 0, stream>>>((const bf16*)xn, w2, b2,
                                                      dmap_raw);
        k_nearest<<<(nb * 2 * 16900 + 255) / 256, 256, 0, stream>>>(
            dmap_raw, dmapA, nb * 2 * 16900);
        k_bilinear<<<(nb * 2 * 16384 + 255) / 256, 256, 0, stream>>>(
            dmapA, dsm, 130, 130, 128, 128,
            (float)(130.0 / 128.0), (float)(130.0 / 128.0), nb * 2 * 16384);
        k_bilinear<<<(nb * 2 * 16900 + 255) / 256, 256, 0, stream>>>(
            dsm, dmap_c, 128, 128, 130, 130,
            (float)(128.0 / 130.0), (float)(128.0 / 130.0), nb * 2 * 16900);
        k_grid<<<nb, 256, 0, stream>>>(dmap_c, grid);
        k_sample<<<dim3(8, 8, nb), 256, 0, stream>>>(feat_c, grid, dst_c);
    }
}

// Round 6
// 677.675 us; speedup vs baseline: 2.5176x; 1.2163x over previous
//
#include <hip/hip_runtime.h>
#include <hip/hip_bf16.h>

typedef __hip_bfloat16 bf16;
typedef __attribute__((ext_vector_type(8))) short bf16x8;
typedef __attribute__((ext_vector_type(4))) float f32x4;

static __device__ __forceinline__ ushort f2bf(float f) {
    uint u = __float_as_uint(f);
    u += 0x7fff + ((u >> 16) & 1);   // RNE
    return (ushort)(u >> 16);
}

static __device__ __forceinline__ void gl_lds16(const void* g, void* l) {
    __builtin_amdgcn_global_load_lds(
        (const __attribute__((address_space(1))) uint*)g,
        (__attribute__((address_space(3))) uint*)l, 16, 0, 0);
}

// featT geometry: padded pixel-major bf16, [yp(258)][xp(264)][64 ic slots]
// value of (y,x,ic) at yp=y+1, xp=x+1, octet slot (ic>>3) ^ (xp&7), elem ic&7.
#define FT_ROW 264
#define FT_IMG ((size_t)258 * 264 * 64)

// ---------------------------------------------------------------------------
// k_wt: w1 (oc,ic,3,3) f32 -> w_bf[tap][oc][ic ^ ((oc&7)<<3)] bf16
// ---------------------------------------------------------------------------
__global__ __launch_bounds__(256) void k_wt(const float* __restrict__ w1,
                                            ushort* __restrict__ w_bf) {
    int i = blockIdx.x * 256 + threadIdx.x;   // i = ((oc*64+ic)*3+dy)*3+dx
    if (i >= 36864) return;
    int oc = i / 576, rem = i - oc * 576;
    int ic = rem / 9, tap = rem - ic * 9;
    w_bf[tap * 4096 + oc * 64 + (ic ^ ((oc & 7) << 3))] = f2bf(w1[i]);
}

// ---------------------------------------------------------------------------
// k_zero: zero the 1-px border of featT (rows 0/257, cols 0/257).
// ---------------------------------------------------------------------------
__global__ __launch_bounds__(256) void k_zero(ushort* __restrict__ featT, int nb) {
    int t = blockIdx.x * 256 + threadIdx.x;
    const int per = 1040 * 8;            // units of 8 ushorts per image
    if (t >= nb * per) return;
    int b = t / per, u = t - b * per;
    int px = u >> 3, oct = u & 7;
    int yp, xp;
    if (px < 264)       { yp = 0;   xp = px; }
    else if (px < 528)  { yp = 257; xp = px - 264; }
    else { int k = px - 528; yp = 1 + (k >> 1); xp = (k & 1) ? 257 : 0; }
    ushort* p = featT + (size_t)b * FT_IMG + ((size_t)yp * FT_ROW + xp) * 64 + oct * 8;
    *(uint4*)p = make_uint4(0u, 0u, 0u, 0u);
}

// ---------------------------------------------------------------------------
// k_tr: feat (nb,64,256,256) f32 -> featT bf16 pixel-major, swizzled.
// ---------------------------------------------------------------------------
__global__ __launch_bounds__(256) void k_tr(const float* __restrict__ feat_c,
                                            ushort* __restrict__ featT) {
    __shared__ ushort s_t[64][72];       // [ic][x], padded
    const int b = blockIdx.z, y = blockIdx.y, x0 = blockIdx.x * 64;
    const int t = threadIdx.x;
    const int xl = t & 63, icg = t >> 6;

    const float* fb = feat_c + (size_t)b * 64 * 65536 + (size_t)y * 256 + x0 + xl;
#pragma unroll
    for (int k = 0; k < 16; ++k) {
        int ic = icg * 16 + k;
        s_t[ic][xl] = f2bf(fb[(size_t)ic * 65536]);
    }
    __syncthreads();

    ushort* ob = featT + (size_t)b * FT_IMG + ((size_t)(y + 1) * FT_ROW + (x0 + 1)) * 64;
#pragma unroll
    for (int u2 = 0; u2 < 2; ++u2) {
        int u = u2 * 256 + t;            // 512 units: (x, octet)
        int x = u >> 3, oct = u & 7;
        int xp7 = (x + 1) & 7;           // (xp&7), since x0 % 64 == 0
        uint p0 = (uint)s_t[oct * 8 + 0][x] | ((uint)s_t[oct * 8 + 1][x] << 16);
        uint p1 = (uint)s_t[oct * 8 + 2][x] | ((uint)s_t[oct * 8 + 3][x] << 16);
        uint p2 = (uint)s_t[oct * 8 + 4][x] | ((uint)s_t[oct * 8 + 5][x] << 16);
        uint p3 = (uint)s_t[oct * 8 + 6][x] | ((uint)s_t[oct * 8 + 7][x] << 16);
        *(uint4*)(ob + (size_t)x * 64 + (oct ^ xp7) * 8) = make_uint4(p0, p1, p2, p3);
    }
}

// ---------------------------------------------------------------------------
// k_conv1 (MFMA + DMA staging): 3x3 conv + bias + BN + ReLU6 + L2-norm.
// Output tile base (unpadded) = x0p; LDS col 0 holds the left halo (x0p-1).
// ---------------------------------------------------------------------------
__global__ __launch_bounds__(256, 2) void k_conv1(
    const ushort* __restrict__ featT, const ushort* __restrict__ w_bf,
    const float* __restrict__ b1, const float* __restrict__ gamma,
    const float* __restrict__ beta, const float* __restrict__ rmean,
    const float* __restrict__ rvar, ushort* __restrict__ xn) {
    __shared__ ushort s_in[6 * 72 * 64];   // 55296 B
    __shared__ ushort s_w[12288];          // 24576 B
    __shared__ float2 s_bn[64];

    const int b   = blockIdx.z;
    const int x0p = blockIdx.x * 64;       // padded col base == unpadded out base
    const int y0  = blockIdx.y * 4;
    const int tid = threadIdx.x;
    const int lane = tid & 63;
    const int w    = tid >> 6;
    const int l15  = lane & 15;
    const int l4   = lane >> 4;

    if (tid < 64) {
        float inv = 1.0f / sqrtf(rvar[tid] + 1e-5f);
        float sA = inv * gamma[tid];
        float sB = (b1[tid] - rmean[tid]) * sA + beta[tid];
        s_bn[tid] = make_float2(sA, sB);
    }

    // ---- A-stage: 6 rows x 9216 B = 54 wave-issues of 1024 B ----
    const ushort* fT = featT + (size_t)b * FT_IMG;
    {
        int aStart = w * 13 + (w < 2 ? w : 2);       // {0,14,28,41}
        int aCnt   = (w < 2) ? 14 : 13;
        for (int q = 0; q < aCnt; ++q) {
            int o = (aStart + q) * 1024;             // byte offset in s_in
            int r = o / 9216;                        // staged row (uniform)
            int rem = o - r * 9216;
            const ushort* g = fT + ((size_t)(y0 + r) * FT_ROW + x0p) * 64 +
                              (rem >> 1) + lane * 8;
            gl_lds16(g, (char*)s_in + o);
        }
    }

    f32x4 acc[4][4];
#pragma unroll
    for (int m = 0; m < 4; m++)
#pragma unroll
        for (int n = 0; n < 4; n++) acc[m][n] = (f32x4){0.f, 0.f, 0.f, 0.f};

    for (int dy = 0; dy < 3; dy++) {
        __syncthreads();
        {   // weight chunk dy: 24576 B = 24 wave-issues
            for (int q = 0; q < 6; ++q) {
                int o = (w * 6 + q) * 1024;
                const ushort* g = w_bf + dy * 12288 + (o >> 1) + lane * 8;
                gl_lds16(g, (char*)s_w + o);
            }
        }
        __syncthreads();
#pragma unroll
        for (int dx = 0; dx < 3; dx++) {
#pragma unroll
            for (int ks = 0; ks < 2; ks++) {
                bf16x8 a[4], bb[4];
#pragma unroll
                for (int m = 0; m < 4; m++) {
                    int c = m * 16 + l15 + dx;
                    int slot = (ks * 4 + l4) ^ (c & 7);
                    a[m] = *(const bf16x8*)&s_in[((w + dy) * 72 + c) * 64 + slot * 8];
                }
#pragma unroll
                for (int n = 0; n < 4; n++) {
                    int oc = n * 16 + l15;
                    int slot = (ks * 4 + l4) ^ (oc & 7);
                    bb[n] = *(const bf16x8*)&s_w[(dx * 64 + oc) * 64 + slot * 8];
                }
#pragma unroll
                for (int m = 0; m < 4; m++)
#pragma unroll
                    for (int n = 0; n < 4; n++)
                        acc[m][n] = __builtin_amdgcn_mfma_f32_16x16x32_bf16(
                            a[m], bb[n], acc[m][n], 0, 0, 0);
            }
        }
    }

    // epilogue: BN + ReLU6 + L2-norm + bf16 store
    float sA[4], sB[4];
#pragma unroll
    for (int n = 0; n < 4; n++) {
        float2 t = s_bn[n * 16 + l15];
        sA[n] = t.x; sB[n] = t.y;
    }
    const int y = y0 + w;
    ushort* xb = xn + (size_t)b * 64 * 65536;

#pragma unroll
    for (int m = 0; m < 4; m++) {
        float vv[4][4];   // [j][n]
        float scj[4];
#pragma unroll
        for (int j = 0; j < 4; j++) {
            float ss = 0.f;
#pragma unroll
            for (int n = 0; n < 4; n++) {
                float v = fmaf(acc[m][n][j], sA[n], sB[n]);
                v = fminf(fmaxf(v, 0.f), 6.f);
                vv[j][n] = v;
                ss = fmaf(v, v, ss);
            }
            ss += __shfl_xor(ss, 1);
            ss += __shfl_xor(ss, 2);
            ss += __shfl_xor(ss, 4);
            ss += __shfl_xor(ss, 8);
            float nrm = sqrtf(ss);
            scj[j] = (nrm > 0.09f) ? (1.0f / (nrm + 9e-8f)) : 0.f;
        }
        int xbase = x0p + m * 16 + l4 * 4;   // FIX: out base is x0p (col 0 = halo)
#pragma unroll
        for (int n = 0; n < 4; n++) {
            uint2 pk;
            pk.x = (uint)f2bf(vv[0][n] * scj[0]) | ((uint)f2bf(vv[1][n] * scj[1]) << 16);
            pk.y = (uint)f2bf(vv[2][n] * scj[2]) | ((uint)f2bf(vv[3][n] * scj[3]) << 16);
            *(uint2*)(xb + (size_t)(n * 16 + l15) * 65536 + y * 256 + xbase) = pk;
        }
    }
}

// ---------------------------------------------------------------------------
// k_conv2: 5x5 valid conv 64->2 + bias + sigmoid. Output (nb,2,252,252) f32.
// ---------------------------------------------------------------------------
__global__ __launch_bounds__(256) void k_conv2(const bf16* __restrict__ xn,
                                               const float* __restrict__ w2,
                                               const float* __restrict__ b2,
                                               float* __restrict__ dmap_raw) {
    __shared__ float s_in[8][400];   // 8 ch x 20x20
    __shared__ float2 s_w[1600];     // (ic*25+tap) -> (w_oc0, w_oc1)

    const int b = blockIdx.z;
    const int bx = blockIdx.x, by = blockIdx.y;
    const int tid = threadIdx.x;
    const int tx = tid & 15, ty = tid >> 4;
    const int ox = bx * 16 + tx, oy = by * 16 + ty;

    for (int i = tid; i < 1600; i += 256)
        s_w[i] = make_float2(w2[i], w2[1600 + i]);

    float a0 = 0.f, a1 = 0.f;
    const bf16* xb = xn + (size_t)b * 64 * 65536;

    for (int c0 = 0; c0 < 64; c0 += 8) {
        __syncthreads();
        for (int i = tid; i < 3200; i += 256) {
            int ic = i / 400, r = i - ic * 400;
            int yy = by * 16 + r / 20, xx = bx * 16 + r % 20;
            float v = 0.f;
            if (yy < 256 && xx < 256)
                v = __bfloat162float(xb[(size_t)(c0 + ic) * 65536 + yy * 256 + xx]);
            s_in[ic][r] = v;
        }
        __syncthreads();
        for (int ic = 0; ic < 8; ic++) {
            const float* base = &s_in[ic][ty * 20 + tx];
            const float2* wp = &s_w[(c0 + ic) * 25];
#pragma unroll
            for (int t = 0; t < 25; t++) {
                float v = base[(t / 5) * 20 + (t % 5)];
                float2 wv = wp[t];
                a0 = fmaf(wv.x, v, a0);
                a1 = fmaf(wv.y, v, a1);
            }
        }
    }

    if (ox < 252 && oy < 252) {
        size_t o = (size_t)(b * 2) * 63504 + (size_t)oy * 252 + ox;
        float v0 = a0 + b2[0], v1 = a1 + b2[1];
        dmap_raw[o] = 1.f / (1.f + expf(-v0));
        dmap_raw[o + 63504] = 1.f / (1.f + expf(-v1));
    }
}

// ---------------------------------------------------------------------------
__global__ __launch_bounds__(256) void k_nearest(const float* __restrict__ dmap_raw,
                                                 float* __restrict__ dmapA,
                                                 int total) {
    int i = blockIdx.x * 256 + threadIdx.x;
    if (i >= total) return;
    int ox = i % 130;
    int t = i / 130;
    int oy = t % 130;
    int bc = t / 130;
    const float SC = (float)(252.0 / 130.0);
    int sy = (int)floorf((float)oy * SC);
    int sx = (int)floorf((float)ox * SC);
    float v = dmap_raw[(size_t)bc * 63504 + sy * 252 + sx];
    float m = (oy >= 1 && oy <= 128 && ox >= 1 && ox <= 128) ? 2.0f : 0.0f;
    dmapA[i] = v + 0.0009f + m;
}

// ---------------------------------------------------------------------------
__global__ __launch_bounds__(256) void k_bilinear(const float* __restrict__ in,
                                                  float* __restrict__ out,
                                                  int IH, int IW, int OH, int OW,
                                                  float sch, float scw, int total) {
    int i = blockIdx.x * 256 + threadIdx.x;
    if (i >= total) return;
    int ox = i % OW;
    int t = i / OW;
    int oy = t % OH;
    int bc = t / OH;
    float sy = ((float)oy + 0.5f) * sch - 0.5f;
    float sx = ((float)ox + 0.5f) * scw - 0.5f;
    float y0f = floorf(sy), x0f = floorf(sx);
    float wy = sy - y0f, wx = sx - x0f;
    int y0 = (int)y0f, x0 = (int)x0f;
    int y1 = y0 + 1, x1 = x0 + 1;
    y0 = max(min(y0, IH - 1), 0);
    y1 = max(min(y1, IH - 1), 0);
    x0 = max(min(x0, IW - 1), 0);
    x1 = max(min(x1, IW - 1), 0);
    const float* p = in + (size_t)bc * IH * IW;
    float top = p[y0 * IW + x0] * (1.f - wx) + p[y0 * IW + x1] * wx;
    float bot = p[y1 * IW + x0] * (1.f - wx) + p[y1 * IW + x1] * wx;
    out[i] = top * (1.f - wy) + bot * wy;
}

// ---------------------------------------------------------------------------
__global__ __launch_bounds__(256) void k_grid(const float* __restrict__ dmap130,
                                              float* __restrict__ grid) {
    int b = blockIdx.x;
    int t = threadIdx.x;
    if (t >= 130) return;
    const float* h = dmap130 + (size_t)(b * 2 + 0) * 16900;
    const float* w = dmap130 + (size_t)(b * 2 + 1) * 16900;
    float* g = grid + (size_t)b * 128 * 128 * 2;

    {
        float s = 0.f;
        for (int r = 0; r < 130; r++) s += h[r * 130 + t];
        float inv = 1.f / s;
        float c = 0.f;
        for (int r = 0; r < 130; r++) {
            c += h[r * 130 + t] * inv;
            if (r >= 1 && r <= 128 && t >= 1 && t <= 128)
                g[((r - 1) * 128 + (t - 1)) * 2 + 1] = c * 2.f - 1.f;
        }
    }
    {
        const float* wrow = w + t * 130;
        float s = 0.f;
        for (int x = 0; x < 130; x++) s += wrow[x];
        float inv = 1.f / s;
        float c = 0.f;
        for (int x = 0; x < 130; x++) {
            c += wrow[x] * inv;
            if (x >= 1 && x <= 128 && t >= 1 && t <= 128)
                g[((t - 1) * 128 + (x - 1)) * 2 + 0] = c * 2.f - 1.f;
        }
    }
}

// ---------------------------------------------------------------------------
__global__ __launch_bounds__(256) void k_sample(const float* __restrict__ feat_c,
                                                const float* __restrict__ grid,
                                                float* __restrict__ dst_c) {
    const int b = blockIdx.z;
    const int x = blockIdx.x * 16 + (threadIdx.x & 15);
    const int y = blockIdx.y * 16 + (threadIdx.x >> 4);

    const float* g = grid + (((size_t)b * 128 + y) * 128 + x) * 2;
    float gx = g[0], gy = g[1];
    float ix = (gx + 1.f) * 128.f - 0.5f;
    float iy = (gy + 1.f) * 128.f - 0.5f;
    float x0f = floorf(ix), y0f = floorf(iy);
    float wx = ix - x0f, wy = iy - y0f;
    int ix0 = (int)x0f, iy0 = (int)y0f;
    int ix1 = ix0 + 1, iy1 = iy0 + 1;
    float vx0 = ((unsigned)ix0 < 256u) ? 1.f : 0.f;
    float vx1 = ((unsigned)ix1 < 256u) ? 1.f : 0.f;
    float vy0 = ((unsigned)iy0 < 256u) ? 1.f : 0.f;
    float vy1 = ((unsigned)iy1 < 256u) ? 1.f : 0.f;
    int cx0 = max(min(ix0, 255), 0), cx1 = max(min(ix1, 255), 0);
    int cy0 = max(min(iy0, 255), 0), cy1 = max(min(iy1, 255), 0);
    float w00 = (1.f - wx) * (1.f - wy) * vx0 * vy0;
    float w01 = wx * (1.f - wy) * vx1 * vy0;
    float w10 = (1.f - wx) * wy * vx0 * vy1;
    float w11 = wx * wy * vx1 * vy1;

    const float* fb = feat_c + (size_t)b * 64 * 65536;
    int o00 = cy0 * 256 + cx0, o01 = cy0 * 256 + cx1;
    int o10 = cy1 * 256 + cx0, o11 = cy1 * 256 + cx1;
    float* d = dst_c + (size_t)b * 64 * 16384 + (size_t)y * 128 + x;
#pragma unroll 4
    for (int c = 0; c < 64; c++) {
        const float* fc = fb + (size_t)c * 65536;
        d[(size_t)c * 16384] = fc[o00] * w00 + fc[o01] * w01 +
                               fc[o10] * w10 + fc[o11] * w11;
    }
}

// ---------------------------------------------------------------------------
static inline size_t align256(size_t x) { return (x + 255) & ~(size_t)255; }

extern "C" void kernel_launch(void* const* d_in, const int* in_sizes, int n_in,
                              void* d_out, int out_size, void* d_ws, size_t ws_size,
                              hipStream_t stream) {
    const float* feat  = (const float*)d_in[0];
    const float* w1    = (const float*)d_in[1];
    const float* b1    = (const float*)d_in[2];
    const float* gamma = (const float*)d_in[3];
    const float* beta  = (const float*)d_in[4];
    const float* rmean = (const float*)d_in[5];
    const float* rvar  = (const float*)d_in[6];
    const float* w2    = (const float*)d_in[7];
    const float* b2    = (const float*)d_in[8];

    float* out = (float*)d_out;                 // reference outputs are f32
    float* out_dst  = out;                      // (16,64,128,128)
    float* out_dmap = out + 16777216;           // (16,2,130,130)

    // pick images-per-chunk nb adaptively from ws_size (deterministic)
    int nb = 1;
    const int cands[5] = {16, 8, 4, 2, 1};
    for (int k = 0; k < 5; ++k) {
        int n = cands[k];
        size_t need = align256((size_t)n * FT_IMG * 2)     // featT bf16 padded
                    + align256((size_t)n * 8388608)        // xn bf16
                    + align256(73728)                      // w_bf
                    + align256((size_t)n * 2 * 63504 * 4)  // dmap_raw
                    + align256((size_t)n * 2 * 16900 * 4)  // dmapA
                    + align256((size_t)n * 2 * 16384 * 4)  // dsm
                    + align256((size_t)n * 131072);        // grid
        if (need <= ws_size) { nb = n; break; }
    }

    char* p = (char*)d_ws;
    ushort* featT   = (ushort*)p; p += align256((size_t)nb * FT_IMG * 2);
    ushort* xn      = (ushort*)p; p += align256((size_t)nb * 8388608);
    ushort* w_bf    = (ushort*)p; p += align256(73728);
    float* dmap_raw = (float*)p;  p += align256((size_t)nb * 2 * 63504 * 4);
    float* dmapA    = (float*)p;  p += align256((size_t)nb * 2 * 16900 * 4);
    float* dsm      = (float*)p;  p += align256((size_t)nb * 2 * 16384 * 4);
    float* grid     = (float*)p;

    k_wt<<<144, 256, 0, stream>>>(w1, w_bf);

    const int nchunks = 16 / nb;
    for (int c = 0; c < nchunks; ++c) {
        const float* feat_c = feat + (size_t)c * nb * 64 * 65536;
        float* dst_c  = out_dst  + (size_t)c * nb * 64 * 16384;
        float* dmap_c = out_dmap + (size_t)c * nb * 2 * 16900;

        k_zero<<<(nb * 8320 + 255) / 256, 256, 0, stream>>>(featT, nb);
        k_tr<<<dim3(4, 256, nb), 256, 0, stream>>>(feat_c, featT);
        k_conv1<<<dim3(4, 64, nb), 256, 0, stream>>>(featT, w_bf, b1, gamma,
                                                     beta, rmean, rvar, xn);
        k_conv2<<<dim3(16, 16, nb), 256, 0, stream>>>((const bf16*)xn, w2, b2,
                                                      dmap_raw);
        k_nearest<<<(nb * 2 * 16900 + 255) / 256, 256, 0, stream>>>(
            dmap_raw, dmapA, nb * 2 * 16900);
        k_bilinear<<<(nb * 2 * 16384 + 255) / 256, 256, 0, stream>>>(
            dmapA, dsm, 130, 130, 128, 128,
            (float)(130.0 / 128.0), (float)(130.0 / 128.0), nb * 2 * 16384);
        k_bilinear<<<(nb * 2 * 16900 + 255) / 256, 256, 0, stream>>>(
            dsm, dmap_c, 128, 128, 130, 130,
            (float)(128.0 / 130.0), (float)(128.0 / 130.0), nb * 2 * 16900);
        k_grid<<<nb, 256, 0, stream>>>(dmap_c, grid);
        k_sample<<<dim3(8, 8, nb), 256, 0, stream>>>(feat_c, grid, dst_c);
    }
}

// Round 7
// 460.352 us; speedup vs baseline: 3.7061x; 1.4721x over previous
//
#include <hip/hip_runtime.h>
#include <hip/hip_bf16.h>

typedef __hip_bfloat16 bf16;
typedef __attribute__((ext_vector_type(8))) short bf16x8;
typedef __attribute__((ext_vector_type(4))) float f32x4;

static __device__ __forceinline__ ushort f2bf(float f) {
    uint u = __float_as_uint(f);
    u += 0x7fff + ((u >> 16) & 1);   // RNE
    return (ushort)(u >> 16);
}

static __device__ __forceinline__ void gl_lds16(const void* g, void* l) {
    __builtin_amdgcn_global_load_lds(
        (const __attribute__((address_space(1))) uint*)g,
        (__attribute__((address_space(3))) uint*)l, 16, 0, 0);
}

// featT geometry: padded pixel-major bf16, [yp(258)][xp(264)][64 ic slots]
// value of (y,x,ic) at yp=y+1, xp=x+1, octet slot (ic>>3) ^ (xp&7), elem ic&7.
#define FT_ROW 264
#define FT_IMG ((size_t)258 * 264 * 64)
// xn geometry: pixel-major bf16 [y(256)][x(256)][64 oc slots], octet ^ (x&7).
#define XN_IMG ((size_t)256 * 256 * 64)

// ---------------------------------------------------------------------------
// k_wt: w1 (oc,ic,3,3) f32 -> w_bf[tap][oc][ic ^ ((oc&7)<<3)] bf16
// ---------------------------------------------------------------------------
__global__ __launch_bounds__(256) void k_wt(const float* __restrict__ w1,
                                            ushort* __restrict__ w_bf) {
    int i = blockIdx.x * 256 + threadIdx.x;   // i = ((oc*64+ic)*3+dy)*3+dx
    if (i >= 36864) return;
    int oc = i / 576, rem = i - oc * 576;
    int ic = rem / 9, tap = rem - ic * 9;
    w_bf[tap * 4096 + oc * 64 + (ic ^ ((oc & 7) << 3))] = f2bf(w1[i]);
}

// ---------------------------------------------------------------------------
// k_wt2: w2 (2,64,5,5) f32 -> w2_bf[tap(25)][oc(2)][ic(64)] bf16 (linear)
// ---------------------------------------------------------------------------
__global__ __launch_bounds__(256) void k_wt2(const float* __restrict__ w2,
                                             ushort* __restrict__ w2_bf) {
    int i = blockIdx.x * 256 + threadIdx.x;   // i = (oc*64+ic)*25 + tap
    if (i >= 3200) return;
    int oc = i / 1600, rem = i - oc * 1600;
    int ic = rem / 25, tap = rem - ic * 25;
    w2_bf[(tap * 2 + oc) * 64 + ic] = f2bf(w2[i]);
}

// ---------------------------------------------------------------------------
// k_zero: zero the 1-px border of featT (rows 0/257, cols 0/257).
// ---------------------------------------------------------------------------
__global__ __launch_bounds__(256) void k_zero(ushort* __restrict__ featT, int nb) {
    int t = blockIdx.x * 256 + threadIdx.x;
    const int per = 1040 * 8;            // units of 8 ushorts per image
    if (t >= nb * per) return;
    int b = t / per, u = t - b * per;
    int px = u >> 3, oct = u & 7;
    int yp, xp;
    if (px < 264)       { yp = 0;   xp = px; }
    else if (px < 528)  { yp = 257; xp = px - 264; }
    else { int k = px - 528; yp = 1 + (k >> 1); xp = (k & 1) ? 257 : 0; }
    ushort* p = featT + (size_t)b * FT_IMG + ((size_t)yp * FT_ROW + xp) * 64 + oct * 8;
    *(uint4*)p = make_uint4(0u, 0u, 0u, 0u);
}

// ---------------------------------------------------------------------------
// k_tr: feat (nb,64,256,256) f32 -> featT bf16 pixel-major, swizzled.
// ---------------------------------------------------------------------------
__global__ __launch_bounds__(256) void k_tr(const float* __restrict__ feat_c,
                                            ushort* __restrict__ featT) {
    __shared__ ushort s_t[64][72];       // [ic][x], padded
    const int b = blockIdx.z, y = blockIdx.y, x0 = blockIdx.x * 64;
    const int t = threadIdx.x;
    const int xl = t & 63, icg = t >> 6;

    const float* fb = feat_c + (size_t)b * 64 * 65536 + (size_t)y * 256 + x0 + xl;
#pragma unroll
    for (int k = 0; k < 16; ++k) {
        int ic = icg * 16 + k;
        s_t[ic][xl] = f2bf(fb[(size_t)ic * 65536]);
    }
    __syncthreads();

    ushort* ob = featT + (size_t)b * FT_IMG + ((size_t)(y + 1) * FT_ROW + (x0 + 1)) * 64;
#pragma unroll
    for (int u2 = 0; u2 < 2; ++u2) {
        int u = u2 * 256 + t;            // 512 units: (x, octet)
        int x = u >> 3, oct = u & 7;
        int xp7 = (x + 1) & 7;           // (xp&7), since x0 % 64 == 0
        uint p0 = (uint)s_t[oct * 8 + 0][x] | ((uint)s_t[oct * 8 + 1][x] << 16);
        uint p1 = (uint)s_t[oct * 8 + 2][x] | ((uint)s_t[oct * 8 + 3][x] << 16);
        uint p2 = (uint)s_t[oct * 8 + 4][x] | ((uint)s_t[oct * 8 + 5][x] << 16);
        uint p3 = (uint)s_t[oct * 8 + 6][x] | ((uint)s_t[oct * 8 + 7][x] << 16);
        *(uint4*)(ob + (size_t)x * 64 + (oct ^ xp7) * 8) = make_uint4(p0, p1, p2, p3);
    }
}

// ---------------------------------------------------------------------------
// k_conv1 (MFMA + DMA staging): 3x3 conv + bias + BN + ReLU6 + L2-norm.
// C[oc row, px col] orientation: mfma(W, X, acc). Writes xn PIXEL-MAJOR
// swizzled (DMA-able by conv2).
// ---------------------------------------------------------------------------
__global__ __launch_bounds__(256, 2) void k_conv1(
    const ushort* __restrict__ featT, const ushort* __restrict__ w_bf,
    const float* __restrict__ b1, const float* __restrict__ gamma,
    const float* __restrict__ beta, const float* __restrict__ rmean,
    const float* __restrict__ rvar, ushort* __restrict__ xn) {
    __shared__ __align__(16) ushort s_in[6 * 72 * 64];   // 55296 B
    __shared__ __align__(16) ushort s_w[12288];          // 24576 B
    __shared__ float2 s_bn[64];

    const int b   = blockIdx.z;
    const int x0p = blockIdx.x * 64;       // padded col base == unpadded out base
    const int y0  = blockIdx.y * 4;
    const int tid = threadIdx.x;
    const int lane = tid & 63;
    const int w    = tid >> 6;
    const int l15  = lane & 15;
    const int l4   = lane >> 4;

    if (tid < 64) {
        float inv = 1.0f / sqrtf(rvar[tid] + 1e-5f);
        float sA = inv * gamma[tid];
        float sB = (b1[tid] - rmean[tid]) * sA + beta[tid];
        s_bn[tid] = make_float2(sA, sB);
    }

    // ---- A-stage: 6 rows x 9216 B = 54 wave-issues of 1024 B ----
    const ushort* fT = featT + (size_t)b * FT_IMG;
    {
        int aStart = w * 13 + (w < 2 ? w : 2);       // {0,14,28,41}
        int aCnt   = (w < 2) ? 14 : 13;
        for (int q = 0; q < aCnt; ++q) {
            int o = (aStart + q) * 1024;             // byte offset in s_in
            int r = o / 9216;                        // staged row (uniform)
            int rem = o - r * 9216;
            const ushort* g = fT + ((size_t)(y0 + r) * FT_ROW + x0p) * 64 +
                              (rem >> 1) + lane * 8;
            gl_lds16(g, (char*)s_in + o);
        }
    }

    f32x4 acc[4][4];
#pragma unroll
    for (int m = 0; m < 4; m++)
#pragma unroll
        for (int n = 0; n < 4; n++) acc[m][n] = (f32x4){0.f, 0.f, 0.f, 0.f};

    for (int dy = 0; dy < 3; dy++) {
        __syncthreads();
        {   // weight chunk dy: 24576 B = 24 wave-issues
            for (int q = 0; q < 6; ++q) {
                int o = (w * 6 + q) * 1024;
                const ushort* g = w_bf + dy * 12288 + (o >> 1) + lane * 8;
                gl_lds16(g, (char*)s_w + o);
            }
        }
        __syncthreads();
#pragma unroll
        for (int dx = 0; dx < 3; dx++) {
#pragma unroll
            for (int ks = 0; ks < 2; ks++) {
                bf16x8 a[4], bb[4];
#pragma unroll
                for (int m = 0; m < 4; m++) {
                    int c = m * 16 + l15 + dx;
                    int slot = (ks * 4 + l4) ^ (c & 7);
                    a[m] = *(const bf16x8*)&s_in[((w + dy) * 72 + c) * 64 + slot * 8];
                }
#pragma unroll
                for (int n = 0; n < 4; n++) {
                    int oc = n * 16 + l15;
                    int slot = (ks * 4 + l4) ^ (oc & 7);
                    bb[n] = *(const bf16x8*)&s_w[(dx * 64 + oc) * 64 + slot * 8];
                }
#pragma unroll
                for (int m = 0; m < 4; m++)
#pragma unroll
                    for (int n = 0; n < 4; n++)   // SWAPPED: C[oc row, px col]
                        acc[m][n] = __builtin_amdgcn_mfma_f32_16x16x32_bf16(
                            bb[n], a[m], acc[m][n], 0, 0, 0);
            }
        }
    }

    // epilogue: C[oc = n*16 + l4*4 + j][px = x0p + m*16 + l15]
    float sA[4][4], sB[4][4];
#pragma unroll
    for (int n = 0; n < 4; n++)
#pragma unroll
        for (int j = 0; j < 4; j++) {
            float2 t = s_bn[n * 16 + l4 * 4 + j];
            sA[n][j] = t.x; sB[n][j] = t.y;
        }
    const int y = y0 + w;
    ushort* xb = xn + (size_t)b * XN_IMG;

#pragma unroll
    for (int m = 0; m < 4; m++) {
        float vv[4][4];
        float ss = 0.f;
#pragma unroll
        for (int n = 0; n < 4; n++)
#pragma unroll
            for (int j = 0; j < 4; j++) {
                float v = fmaf(acc[m][n][j], sA[n][j], sB[n][j]);
                v = fminf(fmaxf(v, 0.f), 6.f);
                vv[n][j] = v;
                ss = fmaf(v, v, ss);
            }
        ss += __shfl_xor(ss, 16);
        ss += __shfl_xor(ss, 32);
        float nrm = sqrtf(ss);
        float sc = (nrm > 0.09f) ? (1.0f / (nrm + 9e-8f)) : 0.f;

        int x = x0p + m * 16 + l15;
        ushort* pb = xb + ((size_t)y * 256 + x) * 64;
        int so = (l4 & 1) * 4;
#pragma unroll
        for (int n = 0; n < 4; n++) {
            int oct = n * 2 + (l4 >> 1);
            int slot = oct ^ (x & 7);
            uint2 pk;
            pk.x = (uint)f2bf(vv[n][0] * sc) | ((uint)f2bf(vv[n][1] * sc) << 16);
            pk.y = (uint)f2bf(vv[n][2] * sc) | ((uint)f2bf(vv[n][3] * sc) << 16);
            *(uint2*)(pb + slot * 8 + so) = pk;
        }
    }
}

// ---------------------------------------------------------------------------
// k_conv2 (MFMA): 5x5 valid conv 64->2 + bias + sigmoid.
// C[oc row, px col]; A = w2 from global (L2-hot), B = xn patches via DMA.
// Block: 4 waves = 4 oy rows x 64 ox. Grid (4, 63, nb).
// ---------------------------------------------------------------------------
__global__ __launch_bounds__(256, 2) void k_conv2(
    const ushort* __restrict__ xn, const ushort* __restrict__ w2_bf,
    const float* __restrict__ b2, float* __restrict__ dmap_raw) {
    __shared__ __align__(16) ushort s_in[8 * 72 * 64];   // 73728 B

    const int b   = blockIdx.z;
    const int x0  = blockIdx.x * 64;
    const int oy0 = blockIdx.y * 4;
    const int tid = threadIdx.x;
    const int lane = tid & 63;
    const int w    = tid >> 6;
    const int l15  = lane & 15;
    const int l4   = lane >> 4;

    // stage 8 rows x 72 px x 64 ic: 72 DMA issues (18 per wave)
    const ushort* xb = xn + (size_t)b * XN_IMG;
    for (int qq = 0; qq < 18; ++qq) {
        int q = w * 18 + qq;
        int r = q / 9, off = q - r * 9;
        const ushort* g = xb + ((size_t)(oy0 + r) * 256 + x0) * 64 +
                          off * 512 + lane * 8;
        gl_lds16(g, (char*)s_in + q * 1024);
    }
    __syncthreads();

    f32x4 acc[4];
#pragma unroll
    for (int n = 0; n < 4; n++) acc[n] = (f32x4){0.f, 0.f, 0.f, 0.f};

    for (int dy = 0; dy < 5; dy++) {
#pragma unroll
        for (int dx = 0; dx < 5; dx++) {
#pragma unroll
            for (int ks = 0; ks < 2; ks++) {
                bf16x8 aw;
                if (l15 < 2)
                    aw = *(const bf16x8*)(w2_bf + ((dy * 5 + dx) * 2 + l15) * 64 +
                                          ks * 32 + l4 * 8);
                else
                    aw = (bf16x8){0, 0, 0, 0, 0, 0, 0, 0};
                bf16x8 bx[4];
#pragma unroll
                for (int n = 0; n < 4; n++) {
                    int px = n * 16 + l15 + dx;
                    int slot = (ks * 4 + l4) ^ (px & 7);
                    bx[n] = *(const bf16x8*)&s_in[((w + dy) * 72 + px) * 64 + slot * 8];
                }
#pragma unroll
                for (int n = 0; n < 4; n++)
                    acc[n] = __builtin_amdgcn_mfma_f32_16x16x32_bf16(
                        aw, bx[n], acc[n], 0, 0, 0);
            }
        }
    }

    // epilogue: rows oc = l4*4 + j -> only l4==0, j<2 are real
    if (l4 == 0) {
        const int oy = oy0 + w;
        float bias0 = b2[0], bias1 = b2[1];
#pragma unroll
        for (int n = 0; n < 4; n++) {
            int ox = x0 + n * 16 + l15;
            if (ox < 252) {
                float v0 = acc[n][0] + bias0;
                float v1 = acc[n][1] + bias1;
                size_t o = (size_t)(b * 2) * 63504 + (size_t)oy * 252 + ox;
                dmap_raw[o] = 1.f / (1.f + expf(-v0));
                dmap_raw[o + 63504] = 1.f / (1.f + expf(-v1));
            }
        }
    }
}

// ---------------------------------------------------------------------------
__global__ __launch_bounds__(256) void k_nearest(const float* __restrict__ dmap_raw,
                                                 float* __restrict__ dmapA,
                                                 int total) {
    int i = blockIdx.x * 256 + threadIdx.x;
    if (i >= total) return;
    int ox = i % 130;
    int t = i / 130;
    int oy = t % 130;
    int bc = t / 130;
    const float SC = (float)(252.0 / 130.0);
    int sy = (int)floorf((float)oy * SC);
    int sx = (int)floorf((float)ox * SC);
    float v = dmap_raw[(size_t)bc * 63504 + sy * 252 + sx];
    float m = (oy >= 1 && oy <= 128 && ox >= 1 && ox <= 128) ? 2.0f : 0.0f;
    dmapA[i] = v + 0.0009f + m;
}

// ---------------------------------------------------------------------------
__global__ __launch_bounds__(256) void k_bilinear(const float* __restrict__ in,
                                                  float* __restrict__ out,
                                                  int IH, int IW, int OH, int OW,
                                                  float sch, float scw, int total) {
    int i = blockIdx.x * 256 + threadIdx.x;
    if (i >= total) return;
    int ox = i % OW;
    int t = i / OW;
    int oy = t % OH;
    int bc = t / OH;
    float sy = ((float)oy + 0.5f) * sch - 0.5f;
    float sx = ((float)ox + 0.5f) * scw - 0.5f;
    float y0f = floorf(sy), x0f = floorf(sx);
    float wy = sy - y0f, wx = sx - x0f;
    int y0 = (int)y0f, x0 = (int)x0f;
    int y1 = y0 + 1, x1 = x0 + 1;
    y0 = max(min(y0, IH - 1), 0);
    y1 = max(min(y1, IH - 1), 0);
    x0 = max(min(x0, IW - 1), 0);
    x1 = max(min(x1, IW - 1), 0);
    const float* p = in + (size_t)bc * IH * IW;
    float top = p[y0 * IW + x0] * (1.f - wx) + p[y0 * IW + x1] * wx;
    float bot = p[y1 * IW + x0] * (1.f - wx) + p[y1 * IW + x1] * wx;
    out[i] = top * (1.f - wy) + bot * wy;
}

// ---------------------------------------------------------------------------
__global__ __launch_bounds__(256) void k_grid(const float* __restrict__ dmap130,
                                              float* __restrict__ grid) {
    int b = blockIdx.x;
    int t = threadIdx.x;
    if (t >= 130) return;
    const float* h = dmap130 + (size_t)(b * 2 + 0) * 16900;
    const float* w = dmap130 + (size_t)(b * 2 + 1) * 16900;
    float* g = grid + (size_t)b * 128 * 128 * 2;

    {
        float s = 0.f;
        for (int r = 0; r < 130; r++) s += h[r * 130 + t];
        float inv = 1.f / s;
        float c = 0.f;
        for (int r = 0; r < 130; r++) {
            c += h[r * 130 + t] * inv;
            if (r >= 1 && r <= 128 && t >= 1 && t <= 128)
                g[((r - 1) * 128 + (t - 1)) * 2 + 1] = c * 2.f - 1.f;
        }
    }
    {
        const float* wrow = w + t * 130;
        float s = 0.f;
        for (int x = 0; x < 130; x++) s += wrow[x];
        float inv = 1.f / s;
        float c = 0.f;
        for (int x = 0; x < 130; x++) {
            c += wrow[x] * inv;
            if (x >= 1 && x <= 128 && t >= 1 && t <= 128)
                g[((t - 1) * 128 + (x - 1)) * 2 + 0] = c * 2.f - 1.f;
        }
    }
}

// ---------------------------------------------------------------------------
__global__ __launch_bounds__(256) void k_sample(const float* __restrict__ feat_c,
                                                const float* __restrict__ grid,
                                                float* __restrict__ dst_c) {
    const int b = blockIdx.z;
    const int x = blockIdx.x * 16 + (threadIdx.x & 15);
    const int y = blockIdx.y * 16 + (threadIdx.x >> 4);

    const float* g = grid + (((size_t)b * 128 + y) * 128 + x) * 2;
    float gx = g[0], gy = g[1];
    float ix = (gx + 1.f) * 128.f - 0.5f;
    float iy = (gy + 1.f) * 128.f - 0.5f;
    float x0f = floorf(ix), y0f = floorf(iy);
    float wx = ix - x0f, wy = iy - y0f;
    int ix0 = (int)x0f, iy0 = (int)y0f;
    int ix1 = ix0 + 1, iy1 = iy0 + 1;
    float vx0 = ((unsigned)ix0 < 256u) ? 1.f : 0.f;
    float vx1 = ((unsigned)ix1 < 256u) ? 1.f : 0.f;
    float vy0 = ((unsigned)iy0 < 256u) ? 1.f : 0.f;
    float vy1 = ((unsigned)iy1 < 256u) ? 1.f : 0.f;
    int cx0 = max(min(ix0, 255), 0), cx1 = max(min(ix1, 255), 0);
    int cy0 = max(min(iy0, 255), 0), cy1 = max(min(iy1, 255), 0);
    float w00 = (1.f - wx) * (1.f - wy) * vx0 * vy0;
    float w01 = wx * (1.f - wy) * vx1 * vy0;
    float w10 = (1.f - wx) * wy * vx0 * vy1;
    float w11 = wx * wy * vx1 * vy1;

    const float* fb = feat_c + (size_t)b * 64 * 65536;
    int o00 = cy0 * 256 + cx0, o01 = cy0 * 256 + cx1;
    int o10 = cy1 * 256 + cx0, o11 = cy1 * 256 + cx1;
    float* d = dst_c + (size_t)b * 64 * 16384 + (size_t)y * 128 + x;
#pragma unroll 4
    for (int c = 0; c < 64; c++) {
        const float* fc = fb + (size_t)c * 65536;
        d[(size_t)c * 16384] = fc[o00] * w00 + fc[o01] * w01 +
                               fc[o10] * w10 + fc[o11] * w11;
    }
}

// ---------------------------------------------------------------------------
static inline size_t align256(size_t x) { return (x + 255) & ~(size_t)255; }

extern "C" void kernel_launch(void* const* d_in, const int* in_sizes, int n_in,
                              void* d_out, int out_size, void* d_ws, size_t ws_size,
                              hipStream_t stream) {
    const float* feat  = (const float*)d_in[0];
    const float* w1    = (const float*)d_in[1];
    const float* b1    = (const float*)d_in[2];
    const float* gamma = (const float*)d_in[3];
    const float* beta  = (const float*)d_in[4];
    const float* rmean = (const float*)d_in[5];
    const float* rvar  = (const float*)d_in[6];
    const float* w2    = (const float*)d_in[7];
    const float* b2    = (const float*)d_in[8];

    float* out = (float*)d_out;                 // reference outputs are f32
    float* out_dst  = out;                      // (16,64,128,128)
    float* out_dmap = out + 16777216;           // (16,2,130,130)

    // pick images-per-chunk nb adaptively from ws_size (deterministic)
    int nb = 1;
    const int cands[5] = {16, 8, 4, 2, 1};
    for (int k = 0; k < 5; ++k) {
        int n = cands[k];
        size_t need = align256((size_t)n * FT_IMG * 2)     // featT bf16 padded
                    + align256((size_t)n * XN_IMG * 2)     // xn bf16 pixel-major
                    + align256(73728)                      // w_bf
                    + align256(12800)                      // w2_bf
                    + align256((size_t)n * 2 * 63504 * 4)  // dmap_raw
                    + align256((size_t)n * 2 * 16900 * 4)  // dmapA
                    + align256((size_t)n * 2 * 16384 * 4)  // dsm
                    + align256((size_t)n * 131072);        // grid
        if (need <= ws_size) { nb = n; break; }
    }

    char* p = (char*)d_ws;
    ushort* featT   = (ushort*)p; p += align256((size_t)nb * FT_IMG * 2);
    ushort* xn      = (ushort*)p; p += align256((size_t)nb * XN_IMG * 2);
    ushort* w_bf    = (ushort*)p; p += align256(73728);
    ushort* w2_bf   = (ushort*)p; p += align256(12800);
    float* dmap_raw = (float*)p;  p += align256((size_t)nb * 2 * 63504 * 4);
    float* dmapA    = (float*)p;  p += align256((size_t)nb * 2 * 16900 * 4);
    float* dsm      = (float*)p;  p += align256((size_t)nb * 2 * 16384 * 4);
    float* grid     = (float*)p;

    k_wt<<<144, 256, 0, stream>>>(w1, w_bf);
    k_wt2<<<13, 256, 0, stream>>>(w2, w2_bf);

    const int nchunks = 16 / nb;
    for (int c = 0; c < nchunks; ++c) {
        const float* feat_c = feat + (size_t)c * nb * 64 * 65536;
        float* dst_c  = out_dst  + (size_t)c * nb * 64 * 16384;
        float* dmap_c = out_dmap + (size_t)c * nb * 2 * 16900;

        k_zero<<<(nb * 8320 + 255) / 256, 256, 0, stream>>>(featT, nb);
        k_tr<<<dim3(4, 256, nb), 256, 0, stream>>>(feat_c, featT);
        k_conv1<<<dim3(4, 64, nb), 256, 0, stream>>>(featT, w_bf, b1, gamma,
                                                     beta, rmean, rvar, xn);
        k_conv2<<<dim3(4, 63, nb), 256, 0, stream>>>(xn, w2_bf, b2, dmap_raw);
        k_nearest<<<(nb * 2 * 16900 + 255) / 256, 256, 0, stream>>>(
            dmap_raw, dmapA, nb * 2 * 16900);
        k_bilinear<<<(nb * 2 * 16384 + 255) / 256, 256, 0, stream>>>(
            dmapA, dsm, 130, 130, 128, 128,
            (float)(130.0 / 128.0), (float)(130.0 / 128.0), nb * 2 * 16384);
        k_bilinear<<<(nb * 2 * 16900 + 255) / 256, 256, 0, stream>>>(
            dsm, dmap_c, 128, 128, 130, 130,
            (float)(128.0 / 130.0), (float)(128.0 / 130.0), nb * 2 * 16900);
        k_grid<<<nb, 256, 0, stream>>>(dmap_c, grid);
        k_sample<<<dim3(8, 8, nb), 256, 0, stream>>>(feat_c, grid, dst_c);
    }
}